// Round 2
// baseline (1702.006 us; speedup 1.0000x reference)
//
#include <hip/hip_runtime.h>
#include <hip/hip_bf16.h>

#define D_ 128

typedef __attribute__((ext_vector_type(8))) short short8;
typedef __attribute__((ext_vector_type(4))) float f32x4;

static __device__ __forceinline__ float lrelu(float x) { return x > 0.f ? x : 0.01f * x; }
static __device__ __forceinline__ short f2bf(float f) {
    __hip_bfloat16 h = __float2bfloat16(f);
    return *reinterpret_cast<short*>(&h);
}

// ---------------- weight prep: f32 -> bf16, transposed, combined ----------------
__global__ void prep_weights(const float* __restrict__ Wn0, const float* __restrict__ We0,
                             const float* __restrict__ Wn1, const float* __restrict__ We1,
                             const float* __restrict__ bn0, const float* __restrict__ be0,
                             const float* __restrict__ bn1, const float* __restrict__ be1,
                             short* __restrict__ W0T, short* __restrict__ W1T,
                             float* __restrict__ b0c, float* __restrict__ b1c) {
    int i = blockIdx.x * 256 + threadIdx.x;
    if (i < 512 * 512) {
        int n = i >> 9, k = i & 511;
        float v = (n < 256) ? Wn0[k * 256 + n] : We0[k * 256 + (n - 256)];
        W0T[i] = f2bf(v);
        return;
    }
    int j = i - 512 * 512;
    if (j < 256 * 256) {
        int n = j >> 8, k = j & 255;
        float v = (n < 128) ? Wn1[k * 128 + n] : We1[k * 128 + (n - 128)];
        W1T[j] = f2bf(v);
        return;
    }
    int t = j - 256 * 256;
    if (t < 512) b0c[t] = (t < 256) ? bn0[t] : be0[t - 256];
    else if (t < 768) b1c[t - 512] = (t < 640) ? bn1[t - 512] : be1[t - 640];
}

// ---------------- per-graph segment sums (float4, 8 rows in flight) ----------------
__global__ void seg_sum(const float* __restrict__ src, const int* __restrict__ counts,
                        int G, int rows, int chunk, float* __restrict__ out) {
    int c4 = threadIdx.x & 31;   // float4 column 0..31
    int rl = threadIdx.x >> 5;   // row lane 0..7
    int r0 = blockIdx.x * chunk + rl;
    int rend = min(rows, blockIdx.x * chunk + chunk);
    int cum[16];
    int s = 0;
    for (int i = 0; i < G; i++) { s += counts[i]; cum[i] = s; }
    f32x4 acc = {0.f, 0.f, 0.f, 0.f};
    int accg = -1;
    for (int r = r0; r < rend; r += 8) {
        int g = 0;
        for (int i = 0; i < G; i++) if (r >= cum[i]) g = i + 1;
        if (g != accg) {
            if (accg >= 0) {
#pragma unroll
                for (int j = 0; j < 4; j++) atomicAdd(&out[accg * D_ + c4 * 4 + j], acc[j]);
            }
            acc = (f32x4){0.f, 0.f, 0.f, 0.f}; accg = g;
        }
        const float4 v = *(const float4*)(src + (long)r * D_ + c4 * 4);
        acc[0] += v.x; acc[1] += v.y; acc[2] += v.z; acc[3] += v.w;
    }
    if (accg >= 0) {
#pragma unroll
        for (int j = 0; j < 4; j++) atomicAdd(&out[accg * D_ + c4 * 4 + j], acc[j]);
    }
}

// ---------------- global-feature MLP (tiny, pure f32) ----------------
__global__ void global_mlp(const float* __restrict__ glbs, const float* __restrict__ sumn,
                           const float* __restrict__ sume,
                           const float* __restrict__ Wg, const float* __restrict__ bg,
                           const float* __restrict__ Wgn, const float* __restrict__ bgn,
                           const float* __restrict__ Wge, const float* __restrict__ bge,
                           const float* __restrict__ Wf, const float* __restrict__ bfv,
                           int G, float* __restrict__ outg) {
    __shared__ float s_tmp[8][384];
    int c = threadIdx.x;  // 128 threads
    for (int r = 0; r < G; r++) {
        float a0 = 0.f, a1 = 0.f, a2 = 0.f;
        for (int k = 0; k < 128; k++) {
            a0 += glbs[r * 128 + k] * Wg[k * 128 + c];
            a1 += sumn[r * 128 + k] * Wgn[k * 128 + c];
            a2 += sume[r * 128 + k] * Wge[k * 128 + c];
        }
        s_tmp[r][c]       = lrelu(a0 + bg[c]);
        s_tmp[r][128 + c] = lrelu(a1 + bgn[c]);
        s_tmp[r][256 + c] = lrelu(a2 + bge[c]);
    }
    __syncthreads();
    for (int r = 0; r < G; r++) {
        float a = 0.f;
        for (int k = 0; k < 384; k++) a += s_tmp[r][k] * Wf[k * 128 + c];
        outg[r * 128 + c] = lrelu(a + bfv[c]);
    }
}

// ---------------- the big fused per-edge MLP ----------------
// block = 64 edges, 512 threads = 8 waves (2 M x 4 N), 64 KiB LDS -> 2 blocks/CU
__launch_bounds__(512, 4)
__global__ void edge_mlp(const float* __restrict__ nodes, const float* __restrict__ edges,
                         const float* __restrict__ glbs,
                         const int* __restrict__ senders, const int* __restrict__ receivers,
                         const int* __restrict__ n_edge, int G,
                         const short* __restrict__ W0T, const short* __restrict__ W1T,
                         const float* __restrict__ b0c, const float* __restrict__ b1c,
                         float* __restrict__ out_nodes, float* __restrict__ out_edges) {
    __shared__ __align__(16) char sH[64 * 1024];  // H [64 rows][512 cols] bf16, swizzled
    __shared__ int s_send[64], s_recv[64], s_gid[64];

    const int tid  = threadIdx.x;
    const int lane = tid & 63;
    const int wid  = tid >> 6;
    const int wm   = wid >> 2;   // 0..1 : 32-row slice
    const int wn   = wid & 3;    // 0..3 : 128-col slice (layer1)
    const int l15  = lane & 15;
    const int lk   = lane >> 4;  // 0..3
    const int base = blockIdx.x * 64;

    if (tid < 64) {
        int e = base + tid;
        s_send[tid] = senders[e];
        s_recv[tid] = receivers[e];
        int cum = 0, g = 0;
        for (int i = 0; i < G; i++) { cum += n_edge[i]; if (e >= cum) g = i + 1; }
        s_gid[tid] = g;
    }
    __syncthreads();

    // ---- layer 1 ----
    f32x4 acc[2][8];
#pragma unroll
    for (int mt = 0; mt < 2; ++mt)
#pragma unroll
        for (int nt = 0; nt < 8; ++nt) acc[mt][nt] = (f32x4){0.f, 0.f, 0.f, 0.f};

#pragma unroll
    for (int c = 0; c < 4; ++c) {  // concat chunk: sender | receiver | edge | global
        const float* srcp[2];
#pragma unroll
        for (int mt = 0; mt < 2; ++mt) {
            int lrow = wm * 32 + mt * 16 + l15;
            int r;
            const float* bp;
            if (c == 0)      { r = s_send[lrow];  bp = nodes; }
            else if (c == 1) { r = s_recv[lrow];  bp = nodes; }
            else if (c == 2) { r = base + lrow;   bp = edges; }
            else             { r = s_gid[lrow];   bp = glbs;  }
            srcp[mt] = bp + (long)r * D_;
        }
#pragma unroll
        for (int kt = 0; kt < 4; ++kt) {
            short8 af[2];
#pragma unroll
            for (int mt = 0; mt < 2; ++mt) {
                const float* p = srcp[mt] + kt * 32 + lk * 8;
                float4 v0 = *(const float4*)(p);
                float4 v1 = *(const float4*)(p + 4);
                short8 a;
                a[0] = f2bf(v0.x); a[1] = f2bf(v0.y); a[2] = f2bf(v0.z); a[3] = f2bf(v0.w);
                a[4] = f2bf(v1.x); a[5] = f2bf(v1.y); a[6] = f2bf(v1.z); a[7] = f2bf(v1.w);
                af[mt] = a;
            }
#pragma unroll
            for (int nt = 0; nt < 8; ++nt) {
                int nrow = wn * 128 + nt * 16 + l15;
                short8 bfr = *(const short8*)(W0T + (long)nrow * 512 + c * 128 + kt * 32 + lk * 8);
#pragma unroll
                for (int mt = 0; mt < 2; ++mt)
                    acc[mt][nt] = __builtin_amdgcn_mfma_f32_16x16x32_bf16(af[mt], bfr, acc[mt][nt], 0, 0, 0);
            }
        }
    }

    // bias + leaky + bf16 -> LDS (XOR swizzle on byte bits 4..6)
#pragma unroll
    for (int nt = 0; nt < 8; ++nt) {
        int col = wn * 128 + nt * 16 + l15;
        float bias = b0c[col];
#pragma unroll
        for (int mt = 0; mt < 2; ++mt) {
#pragma unroll
            for (int q = 0; q < 4; ++q) {
                int row = wm * 32 + mt * 16 + lk * 4 + q;
                float v = lrelu(acc[mt][nt][q] + bias);
                int off = row * 1024 + ((col * 2) ^ ((row & 7) << 4));
                *(short*)(sH + off) = f2bf(v);
            }
        }
    }
    __syncthreads();

    // ---- layer 2 ----
    const int branch = wn >> 1;  // 0 = node-msg, 1 = edge-update
    const int halfn  = wn & 1;
    f32x4 acc2[2][4];
#pragma unroll
    for (int mt = 0; mt < 2; ++mt)
#pragma unroll
        for (int nt = 0; nt < 4; ++nt) acc2[mt][nt] = (f32x4){0.f, 0.f, 0.f, 0.f};

#pragma unroll
    for (int kt = 0; kt < 8; ++kt) {
        short8 af[2];
#pragma unroll
        for (int mt = 0; mt < 2; ++mt) {
            int row = wm * 32 + mt * 16 + l15;
            int kbyte = (branch * 256 + kt * 32 + lk * 8) * 2;
            int off = row * 1024 + (kbyte ^ ((row & 7) << 4));
            af[mt] = *(const short8*)(sH + off);
        }
#pragma unroll
        for (int nt = 0; nt < 4; ++nt) {
            int ncl = halfn * 64 + nt * 16 + l15;
            short8 bfr = *(const short8*)(W1T + (long)(branch * 128 + ncl) * 256 + kt * 32 + lk * 8);
#pragma unroll
            for (int mt = 0; mt < 2; ++mt)
                acc2[mt][nt] = __builtin_amdgcn_mfma_f32_16x16x32_bf16(af[mt], bfr, acc2[mt][nt], 0, 0, 0);
        }
    }

    // epilogue
#pragma unroll
    for (int nt = 0; nt < 4; ++nt) {
        int ncl = halfn * 64 + nt * 16 + l15;
        float bias = b1c[branch * 128 + ncl];
#pragma unroll
        for (int mt = 0; mt < 2; ++mt) {
#pragma unroll
            for (int q = 0; q < 4; ++q) {
                int row = wm * 32 + mt * 16 + lk * 4 + q;
                float v = lrelu(acc2[mt][nt][q] + bias);
                if (branch == 0) {
                    atomicAdd(&out_nodes[(long)s_recv[row] * D_ + ncl], v);
                } else {
                    out_edges[(long)(base + row) * D_ + ncl] = v;
                }
            }
        }
    }
}

extern "C" void kernel_launch(void* const* d_in, const int* in_sizes, int n_in,
                              void* d_out, int out_size, void* d_ws, size_t ws_size,
                              hipStream_t stream) {
    const float* nodes     = (const float*)d_in[0];
    const float* edges     = (const float*)d_in[1];
    const float* glbs      = (const float*)d_in[2];
    const int*   senders   = (const int*)d_in[3];
    const int*   receivers = (const int*)d_in[4];
    const int*   n_node    = (const int*)d_in[5];
    const int*   n_edge    = (const int*)d_in[6];
    const float* Wn0 = (const float*)d_in[7];
    const float* bn0 = (const float*)d_in[8];
    const float* Wn1 = (const float*)d_in[9];
    const float* bn1 = (const float*)d_in[10];
    const float* We0 = (const float*)d_in[11];
    const float* be0 = (const float*)d_in[12];
    const float* We1 = (const float*)d_in[13];
    const float* be1 = (const float*)d_in[14];
    const float* Wgn = (const float*)d_in[15];
    const float* bgn = (const float*)d_in[16];
    const float* Wge = (const float*)d_in[17];
    const float* bge = (const float*)d_in[18];
    const float* Wg  = (const float*)d_in[19];
    const float* bg  = (const float*)d_in[20];
    const float* Wf  = (const float*)d_in[21];
    const float* bfv = (const float*)d_in[22];

    const int N = in_sizes[0] / 128;
    const int E = in_sizes[1] / 128;
    const int G = in_sizes[2] / 128;

    char*  ws   = (char*)d_ws;
    short* W0T  = (short*)(ws);             // 512*512*2 = 524288
    short* W1T  = (short*)(ws + 524288);    // 256*256*2 = 131072
    float* b0c  = (float*)(ws + 655360);    // 2048
    float* b1c  = (float*)(ws + 657408);    // 1024
    float* sumn = (float*)(ws + 658432);    // 4096
    float* sume = (float*)(ws + 662528);    // 4096

    float* out_nodes = (float*)d_out;
    float* out_edges = out_nodes + (long)N * 128;
    float* out_glb   = out_edges + (long)E * 128;

    hipMemsetAsync(out_nodes, 0, (size_t)N * 128 * sizeof(float), stream);
    hipMemsetAsync(sumn, 0, 8192, stream);

    prep_weights<<<1283, 256, 0, stream>>>(Wn0, We0, Wn1, We1, bn0, be0, bn1, be1,
                                           W0T, W1T, b0c, b1c);

    seg_sum<<<(N + 127) / 128, 256, 0, stream>>>(nodes, n_node, G, N, 128, sumn);
    seg_sum<<<(E + 255) / 256, 256, 0, stream>>>(edges, n_edge, G, E, 256, sume);

    edge_mlp<<<E / 64, 512, 0, stream>>>(nodes, edges, glbs, senders, receivers, n_edge, G,
                                         W0T, W1T, b0c, b1c, out_nodes, out_edges);

    global_mlp<<<1, 128, 0, stream>>>(glbs, sumn, sume, Wg, bg, Wgn, bgn, Wge, bge, Wf, bfv,
                                      G, out_glb);
}

// Round 3
// 1198.637 us; speedup vs baseline: 1.4200x; 1.4200x over previous
//
#include <hip/hip_runtime.h>
#include <hip/hip_bf16.h>

#define D_ 128

typedef __attribute__((ext_vector_type(8))) short short8;
typedef __attribute__((ext_vector_type(4))) float f32x4;
typedef __attribute__((address_space(1))) const unsigned int g_u32;
typedef __attribute__((address_space(3))) unsigned int l_u32;

static __device__ __forceinline__ float lrelu(float x) { return x > 0.f ? x : 0.01f * x; }
static __device__ __forceinline__ short f2bf(float f) {
    __hip_bfloat16 h = __float2bfloat16(f);
    return *reinterpret_cast<short*>(&h);
}
static __device__ __forceinline__ unsigned short f2bfu(float f) {
    __hip_bfloat16 h = __float2bfloat16(f);
    return *reinterpret_cast<unsigned short*>(&h);
}

// ---------------- prep: weights f32->bf16 transposed+combined, nodes/glbs -> bf16 ----------------
__global__ void prep(const float* __restrict__ Wn0, const float* __restrict__ We0,
                     const float* __restrict__ Wn1, const float* __restrict__ We1,
                     const float* __restrict__ bn0, const float* __restrict__ be0,
                     const float* __restrict__ bn1, const float* __restrict__ be1,
                     const float* __restrict__ nodes, const float* __restrict__ glbs,
                     long nq,
                     short* __restrict__ W0T, short* __restrict__ W1T,
                     float* __restrict__ b0c, float* __restrict__ b1c,
                     unsigned short* __restrict__ nodes_bf, unsigned short* __restrict__ glbs_bf) {
    long i = (long)blockIdx.x * 256 + threadIdx.x;
    if (i < nq) {  // nodes: 4 elems per thread
        float4 v = ((const float4*)nodes)[i];
        short4 o;
        o.x = f2bf(v.x); o.y = f2bf(v.y); o.z = f2bf(v.z); o.w = f2bf(v.w);
        ((short4*)nodes_bf)[i] = o;
        return;
    }
    long j = i - nq;
    if (j < 512 * 512) {
        int n = (int)(j >> 9), k = (int)(j & 511);
        float v = (n < 256) ? Wn0[k * 256 + n] : We0[k * 256 + (n - 256)];
        W0T[j] = f2bf(v);
        return;
    }
    j -= 512 * 512;
    if (j < 256 * 256) {
        int n = (int)(j >> 8), k = (int)(j & 255);
        float v = (n < 128) ? Wn1[k * 128 + n] : We1[k * 128 + (n - 128)];
        W1T[j] = f2bf(v);
        return;
    }
    j -= 256 * 256;
    if (j < 512) { b0c[j] = (j < 256) ? bn0[j] : be0[j - 256]; return; }
    if (j < 768) { int t = (int)j - 512; b1c[t] = (t < 128) ? bn1[t] : be1[t - 128]; return; }
    j -= 768;
    if (j < 1024) glbs_bf[j] = f2bfu(glbs[j]);
}

// ---------------- per-graph segment sums (float4, 8 rows in flight, no scratch arrays) ----------------
__global__ void seg_sum(const float* __restrict__ src, const int* __restrict__ counts,
                        int G, int rows, int chunk, float* __restrict__ out) {
    int c4 = threadIdx.x & 31;   // float4 column 0..31
    int rl = threadIdx.x >> 5;   // row lane 0..7
    int r0 = blockIdx.x * chunk + rl;
    int rend = min(rows, blockIdx.x * chunk + chunk);
    int s_ = 0;
    int cu0 = 0x7fffffff, cu1 = 0x7fffffff, cu2 = 0x7fffffff, cu3 = 0x7fffffff;
    int cu4 = 0x7fffffff, cu5 = 0x7fffffff, cu6 = 0x7fffffff, cu7 = 0x7fffffff;
#define CUF(I, CU) if (I < G) { s_ += counts[I]; CU = s_; }
    CUF(0, cu0) CUF(1, cu1) CUF(2, cu2) CUF(3, cu3)
    CUF(4, cu4) CUF(5, cu5) CUF(6, cu6) CUF(7, cu7)
#undef CUF
    f32x4 acc = {0.f, 0.f, 0.f, 0.f};
    int accg = -1;
    for (int r = r0; r < rend; r += 8) {
        int g = (r >= cu0) + (r >= cu1) + (r >= cu2) + (r >= cu3)
              + (r >= cu4) + (r >= cu5) + (r >= cu6) + (r >= cu7);
        if (g != accg) {
            if (accg >= 0) {
#pragma unroll
                for (int j = 0; j < 4; j++) atomicAdd(&out[accg * D_ + c4 * 4 + j], acc[j]);
            }
            acc = (f32x4){0.f, 0.f, 0.f, 0.f}; accg = g;
        }
        const float4 v = *(const float4*)(src + (long)r * D_ + c4 * 4);
        acc[0] += v.x; acc[1] += v.y; acc[2] += v.z; acc[3] += v.w;
    }
    if (accg >= 0) {
#pragma unroll
        for (int j = 0; j < 4; j++) atomicAdd(&out[accg * D_ + c4 * 4 + j], acc[j]);
    }
}

// ---------------- global-feature MLP (one block per graph) ----------------
__global__ void global_mlp(const float* __restrict__ glbs, const float* __restrict__ sumn,
                           const float* __restrict__ sume,
                           const float* __restrict__ Wg, const float* __restrict__ bg,
                           const float* __restrict__ Wgn, const float* __restrict__ bgn,
                           const float* __restrict__ Wge, const float* __restrict__ bge,
                           const float* __restrict__ Wf, const float* __restrict__ bfv,
                           float* __restrict__ outg) {
    __shared__ float s_tmp[384];
    int r = blockIdx.x;
    int c = threadIdx.x;  // 128 threads
    float a0 = 0.f, a1 = 0.f, a2 = 0.f;
    for (int k = 0; k < 128; k++) {
        a0 += glbs[r * 128 + k] * Wg[k * 128 + c];
        a1 += sumn[r * 128 + k] * Wgn[k * 128 + c];
        a2 += sume[r * 128 + k] * Wge[k * 128 + c];
    }
    s_tmp[c]       = lrelu(a0 + bg[c]);
    s_tmp[128 + c] = lrelu(a1 + bgn[c]);
    s_tmp[256 + c] = lrelu(a2 + bge[c]);
    __syncthreads();
    float a = 0.f;
    for (int k = 0; k < 384; k++) a += s_tmp[k] * Wf[k * 128 + c];
    outg[r * 128 + c] = lrelu(a + bfv[c]);
}

// ---------------- fused per-edge MLP ----------------
// block = 128 edges, 512 threads = 8 waves (2M x 4N), LDS = X tile then H tile (128 KiB shared)
// stage: X[128 rows][512 k] bf16, swizzled (slot p of row e holds k-subchunk p^(e&7), 16B units)
__launch_bounds__(512, 2)
__global__ void edge_mlp(const unsigned short* __restrict__ nodes_bf,
                         const float* __restrict__ edges,
                         const unsigned short* __restrict__ glbs_bf,
                         const int* __restrict__ senders, const int* __restrict__ receivers,
                         const int* __restrict__ n_edge, int G,
                         const short* __restrict__ W0T, const short* __restrict__ W1T,
                         const float* __restrict__ b0c, const float* __restrict__ b1c,
                         float* __restrict__ out_nodes, float* __restrict__ out_edges) {
    __shared__ __align__(16) char sX[128 * 1024];
    __shared__ int s_recv[128];

    const int tid  = threadIdx.x;
    const int lane = tid & 63;
    const int wid  = tid >> 6;
    const int wm   = wid >> 2;   // 0..1 : 64-row slice
    const int wn   = wid & 3;    // 0..3 : 128-col slice (layer1)
    const int l15  = lane & 15;
    const int lk   = lane >> 4;  // 0..3 (source-chunk id during staging)
    const int base = blockIdx.x * 128;

    if (tid < 128) s_recv[tid] = receivers[base + tid];

    // cumulative edge counts in named registers (G <= 8)
    int s_ = 0;
    int cu0 = 0x7fffffff, cu1 = 0x7fffffff, cu2 = 0x7fffffff, cu3 = 0x7fffffff;
    int cu4 = 0x7fffffff, cu5 = 0x7fffffff, cu6 = 0x7fffffff, cu7 = 0x7fffffff;
#define CUF(I, CU) if (I < G) { s_ += n_edge[I]; CU = s_; }
    CUF(0, cu0) CUF(1, cu1) CUF(2, cu2) CUF(3, cu3)
    CUF(4, cu4) CUF(5, cu5) CUF(6, cu6) CUF(7, cu7)
#undef CUF

    // ---- stage X into LDS (each wave stages one row per round) ----
#pragma unroll
    for (int r = 0; r < 16; ++r) {
        const int e  = r * 8 + wid;      // wave-uniform row
        const int ge = base + e;
        const int snd = senders[ge];
        const int rcv = receivers[ge];
        const int g = (ge >= cu0) + (ge >= cu1) + (ge >= cu2) + (ge >= cu3)
                    + (ge >= cu4) + (ge >= cu5) + (ge >= cu6) + (ge >= cu7);
        char* dst = sX + e * 1024;       // wave-uniform LDS base; HW adds lane*16
        if (lk == 2) {
            // edges are f32: load+convert+swizzled ds_write (position XORed, natural content)
            const float* fp = edges + (long)ge * 128 + l15 * 8;
            float4 v0 = *(const float4*)fp;
            float4 v1 = *(const float4*)(fp + 4);
            short8 a;
            a[0] = f2bf(v0.x); a[1] = f2bf(v0.y); a[2] = f2bf(v0.z); a[3] = f2bf(v0.w);
            a[4] = f2bf(v1.x); a[5] = f2bf(v1.y); a[6] = f2bf(v1.z); a[7] = f2bf(v1.w);
            *(short8*)(sX + e * 1024 + ((lane * 16) ^ ((e & 7) << 4))) = a;
        } else {
            // bf16 sources: global_load_lds (position = lane, content pre-swizzled on source side)
            const int w = l15 ^ (e & 7);
            const unsigned short* bp = (lk == 0) ? nodes_bf + (long)snd * 128
                                     : (lk == 1) ? nodes_bf + (long)rcv * 128
                                                 : glbs_bf + (long)g * 128;
            __builtin_amdgcn_global_load_lds((g_u32*)(bp + w * 8), (l_u32*)dst, 16, 0, 0);
        }
    }
    __syncthreads();

    // ---- layer 1: X[128x512] @ W0c[512x512] ----
    f32x4 acc[4][8];
#pragma unroll
    for (int mt = 0; mt < 4; ++mt)
#pragma unroll
        for (int nt = 0; nt < 8; ++nt) acc[mt][nt] = (f32x4){0.f, 0.f, 0.f, 0.f};

#pragma unroll
    for (int t = 0; t < 16; ++t) {
        short8 bfr[8];
#pragma unroll
        for (int nt = 0; nt < 8; ++nt) {
            int n = wn * 128 + nt * 16 + l15;
            bfr[nt] = *(const short8*)(W0T + (long)n * 512 + t * 32 + lk * 8);
        }
#pragma unroll
        for (int mt = 0; mt < 4; ++mt) {
            int row = wm * 64 + mt * 16 + l15;
            short8 af = *(const short8*)(sX + row * 1024 + ((t * 64 + lk * 16) ^ ((row & 7) << 4)));
#pragma unroll
            for (int nt = 0; nt < 8; ++nt)
                acc[mt][nt] = __builtin_amdgcn_mfma_f32_16x16x32_bf16(af, bfr[nt], acc[mt][nt], 0, 0, 0);
        }
    }
    __syncthreads();  // all X reads done; sX can be overwritten by H

    // bias + leaky + bf16 -> LDS H (same geometry/swizzle as X)
#pragma unroll
    for (int nt = 0; nt < 8; ++nt) {
        int col = wn * 128 + nt * 16 + l15;
        float bias = b0c[col];
#pragma unroll
        for (int mt = 0; mt < 4; ++mt) {
#pragma unroll
            for (int q = 0; q < 4; ++q) {
                int row = wm * 64 + mt * 16 + lk * 4 + q;
                float v = lrelu(acc[mt][nt][q] + bias);
                *(short*)(sX + row * 1024 + ((col * 2) ^ ((row & 7) << 4))) = f2bf(v);
            }
        }
    }
    __syncthreads();

    // ---- layer 2 ----
    const int branch = wn >> 1;  // 0 = node-msg, 1 = edge-update
    const int halfn  = wn & 1;
    f32x4 acc2[4][4];
#pragma unroll
    for (int mt = 0; mt < 4; ++mt)
#pragma unroll
        for (int nt = 0; nt < 4; ++nt) acc2[mt][nt] = (f32x4){0.f, 0.f, 0.f, 0.f};

#pragma unroll
    for (int kt = 0; kt < 8; ++kt) {
        short8 bfr2[4];
#pragma unroll
        for (int nt = 0; nt < 4; ++nt) {
            int ncl = halfn * 64 + nt * 16 + l15;
            bfr2[nt] = *(const short8*)(W1T + (long)(branch * 128 + ncl) * 256 + kt * 32 + lk * 8);
        }
#pragma unroll
        for (int mt = 0; mt < 4; ++mt) {
            int row = wm * 64 + mt * 16 + l15;
            int kbyte = (branch * 256 + kt * 32 + lk * 8) * 2;
            short8 af = *(const short8*)(sX + row * 1024 + (kbyte ^ ((row & 7) << 4)));
#pragma unroll
            for (int nt = 0; nt < 4; ++nt)
                acc2[mt][nt] = __builtin_amdgcn_mfma_f32_16x16x32_bf16(af, bfr2[nt], acc2[mt][nt], 0, 0, 0);
        }
    }

    // epilogue
#pragma unroll
    for (int nt = 0; nt < 4; ++nt) {
        int ncl = halfn * 64 + nt * 16 + l15;
        float bias = b1c[branch * 128 + ncl];
#pragma unroll
        for (int mt = 0; mt < 4; ++mt) {
#pragma unroll
            for (int q = 0; q < 4; ++q) {
                int row = wm * 64 + mt * 16 + lk * 4 + q;
                float v = lrelu(acc2[mt][nt][q] + bias);
                if (branch == 0) {
                    atomicAdd(&out_nodes[(long)s_recv[row] * D_ + ncl], v);
                } else {
                    out_edges[(long)(base + row) * D_ + ncl] = v;
                }
            }
        }
    }
}

extern "C" void kernel_launch(void* const* d_in, const int* in_sizes, int n_in,
                              void* d_out, int out_size, void* d_ws, size_t ws_size,
                              hipStream_t stream) {
    const float* nodes     = (const float*)d_in[0];
    const float* edges     = (const float*)d_in[1];
    const float* glbs      = (const float*)d_in[2];
    const int*   senders   = (const int*)d_in[3];
    const int*   receivers = (const int*)d_in[4];
    const int*   n_node    = (const int*)d_in[5];
    const int*   n_edge    = (const int*)d_in[6];
    const float* Wn0 = (const float*)d_in[7];
    const float* bn0 = (const float*)d_in[8];
    const float* Wn1 = (const float*)d_in[9];
    const float* bn1 = (const float*)d_in[10];
    const float* We0 = (const float*)d_in[11];
    const float* be0 = (const float*)d_in[12];
    const float* We1 = (const float*)d_in[13];
    const float* be1 = (const float*)d_in[14];
    const float* Wgn = (const float*)d_in[15];
    const float* bgn = (const float*)d_in[16];
    const float* Wge = (const float*)d_in[17];
    const float* bge = (const float*)d_in[18];
    const float* Wg  = (const float*)d_in[19];
    const float* bg  = (const float*)d_in[20];
    const float* Wf  = (const float*)d_in[21];
    const float* bfv = (const float*)d_in[22];

    const int N = in_sizes[0] / 128;
    const int E = in_sizes[1] / 128;
    const int G = in_sizes[2] / 128;

    char*  ws   = (char*)d_ws;
    short* W0T  = (short*)(ws);                      // 512*512*2 = 524288
    short* W1T  = (short*)(ws + 524288);             // 256*256*2 = 131072
    float* b0c  = (float*)(ws + 655360);             // 2048
    float* b1c  = (float*)(ws + 657408);             // 1024
    float* sumn = (float*)(ws + 658432);             // 4096
    float* sume = (float*)(ws + 662528);             // 4096
    unsigned short* glbs_bf  = (unsigned short*)(ws + 666624);   // 2048
    unsigned short* nodes_bf = (unsigned short*)(ws + 669696);   // N*128*2 = 6.4 MB
    // total ws used ~ 7.07 MB

    float* out_nodes = (float*)d_out;
    float* out_edges = out_nodes + (long)N * 128;
    float* out_glb   = out_edges + (long)E * 128;

    hipMemsetAsync(out_nodes, 0, (size_t)N * 128 * sizeof(float), stream);
    hipMemsetAsync(sumn, 0, 8192, stream);

    const long nq = (long)N * 32;  // float4 count for node conversion
    const long prep_items = nq + 512 * 512 + 256 * 256 + 768 + 1024;
    prep<<<(int)((prep_items + 255) / 256), 256, 0, stream>>>(
        Wn0, We0, Wn1, We1, bn0, be0, bn1, be1, nodes, glbs, nq,
        W0T, W1T, b0c, b1c, nodes_bf, glbs_bf);

    edge_mlp<<<E / 128, 512, 0, stream>>>(nodes_bf, edges, glbs_bf, senders, receivers, n_edge, G,
                                          W0T, W1T, b0c, b1c, out_nodes, out_edges);

    seg_sum<<<(N + 127) / 128, 256, 0, stream>>>(nodes, n_node, G, N, 128, sumn);
    seg_sum<<<(E + 255) / 256, 256, 0, stream>>>(edges, n_edge, G, E, 256, sume);

    global_mlp<<<G, 128, 0, stream>>>(glbs, sumn, sume, Wg, bg, Wgn, bgn, Wge, bge, Wf, bfv,
                                      out_glb);
}

// Round 4
// 1173.474 us; speedup vs baseline: 1.4504x; 1.0214x over previous
//
#include <hip/hip_runtime.h>
#include <hip/hip_bf16.h>

#define D_ 128

typedef __attribute__((ext_vector_type(8))) short short8;
typedef __attribute__((ext_vector_type(4))) float f32x4;
typedef __attribute__((address_space(1))) const unsigned int g_u32;
typedef __attribute__((address_space(3))) unsigned int l_u32;

static __device__ __forceinline__ float lrelu(float x) { return x > 0.f ? x : 0.01f * x; }
static __device__ __forceinline__ short f2bf(float f) {
    __hip_bfloat16 h = __float2bfloat16(f);
    return *reinterpret_cast<short*>(&h);
}
static __device__ __forceinline__ unsigned short f2bfu(float f) {
    __hip_bfloat16 h = __float2bfloat16(f);
    return *reinterpret_cast<unsigned short*>(&h);
}

// ---------------- prep: weights f32->bf16 transposed+combined, nodes/glbs -> bf16 ----------------
__global__ void prep(const float* __restrict__ Wn0, const float* __restrict__ We0,
                     const float* __restrict__ Wn1, const float* __restrict__ We1,
                     const float* __restrict__ bn0, const float* __restrict__ be0,
                     const float* __restrict__ bn1, const float* __restrict__ be1,
                     const float* __restrict__ nodes, const float* __restrict__ glbs,
                     long nq,
                     short* __restrict__ W0T, short* __restrict__ W1T,
                     float* __restrict__ b0c, float* __restrict__ b1c,
                     unsigned short* __restrict__ nodes_bf, unsigned short* __restrict__ glbs_bf) {
    long i = (long)blockIdx.x * 256 + threadIdx.x;
    if (i < nq) {  // nodes: 4 elems per thread
        float4 v = ((const float4*)nodes)[i];
        short4 o;
        o.x = f2bf(v.x); o.y = f2bf(v.y); o.z = f2bf(v.z); o.w = f2bf(v.w);
        ((short4*)nodes_bf)[i] = o;
        return;
    }
    long j = i - nq;
    if (j < 512 * 512) {
        int n = (int)(j >> 9), k = (int)(j & 511);
        float v = (n < 256) ? Wn0[k * 256 + n] : We0[k * 256 + (n - 256)];
        W0T[j] = f2bf(v);
        return;
    }
    j -= 512 * 512;
    if (j < 256 * 256) {
        int n = (int)(j >> 8), k = (int)(j & 255);
        float v = (n < 128) ? Wn1[k * 128 + n] : We1[k * 128 + (n - 128)];
        W1T[j] = f2bf(v);
        return;
    }
    j -= 256 * 256;
    if (j < 512) { b0c[j] = (j < 256) ? bn0[j] : be0[j - 256]; return; }
    if (j < 768) { int t = (int)j - 512; b1c[t] = (t < 128) ? bn1[t] : be1[t - 128]; return; }
    j -= 768;
    if (j < 1024) glbs_bf[j] = f2bfu(glbs[j]);
}

// ---------------- counting sort of edges by receiver ----------------
__global__ void hist_recv(const int* __restrict__ receivers, int E_, int* __restrict__ cnt) {
    int e = blockIdx.x * 256 + threadIdx.x;
    if (e < E_) atomicAdd(&cnt[receivers[e]], 1);
}

__global__ void scan_counts(const int* __restrict__ cnt, int N_, int* __restrict__ off) {
    __shared__ int part[256];
    int t = threadIdx.x;
    int chunk = (N_ + 255) / 256;
    int b = t * chunk, e = min(N_, b + chunk);
    int s = 0;
    for (int i = b; i < e; i++) s += cnt[i];
    part[t] = s;
    __syncthreads();
    for (int o = 1; o < 256; o <<= 1) {
        int v = (t >= o) ? part[t - o] : 0;
        __syncthreads();
        part[t] += v;
        __syncthreads();
    }
    int run = part[t] - s;  // exclusive prefix
    for (int i = b; i < e; i++) { off[i] = run; run += cnt[i]; }
}

__global__ void place_edges(const int* __restrict__ receivers, int E_,
                            int* __restrict__ off, int* __restrict__ sorted) {
    int e = blockIdx.x * 256 + threadIdx.x;
    if (e < E_) {
        int p = atomicAdd(&off[receivers[e]], 1);
        sorted[p] = e;
    }
}

// ---------------- per-graph segment sums ----------------
__global__ void seg_sum(const float* __restrict__ src, const int* __restrict__ counts,
                        int G, int rows, int chunk, float* __restrict__ out) {
    int c4 = threadIdx.x & 31;
    int rl = threadIdx.x >> 5;
    int r0 = blockIdx.x * chunk + rl;
    int rend = min(rows, blockIdx.x * chunk + chunk);
    int s_ = 0;
    int cu0 = 0x7fffffff, cu1 = 0x7fffffff, cu2 = 0x7fffffff, cu3 = 0x7fffffff;
    int cu4 = 0x7fffffff, cu5 = 0x7fffffff, cu6 = 0x7fffffff, cu7 = 0x7fffffff;
#define CUF(I, CU) if (I < G) { s_ += counts[I]; CU = s_; }
    CUF(0, cu0) CUF(1, cu1) CUF(2, cu2) CUF(3, cu3)
    CUF(4, cu4) CUF(5, cu5) CUF(6, cu6) CUF(7, cu7)
#undef CUF
    f32x4 acc = {0.f, 0.f, 0.f, 0.f};
    int accg = -1;
    for (int r = r0; r < rend; r += 8) {
        int g = (r >= cu0) + (r >= cu1) + (r >= cu2) + (r >= cu3)
              + (r >= cu4) + (r >= cu5) + (r >= cu6) + (r >= cu7);
        if (g != accg) {
            if (accg >= 0) {
#pragma unroll
                for (int j = 0; j < 4; j++) atomicAdd(&out[accg * D_ + c4 * 4 + j], acc[j]);
            }
            acc = (f32x4){0.f, 0.f, 0.f, 0.f}; accg = g;
        }
        const float4 v = *(const float4*)(src + (long)r * D_ + c4 * 4);
        acc[0] += v.x; acc[1] += v.y; acc[2] += v.z; acc[3] += v.w;
    }
    if (accg >= 0) {
#pragma unroll
        for (int j = 0; j < 4; j++) atomicAdd(&out[accg * D_ + c4 * 4 + j], acc[j]);
    }
}

// ---------------- global-feature MLP (one block per graph) ----------------
__global__ void global_mlp(const float* __restrict__ glbs, const float* __restrict__ sumn,
                           const float* __restrict__ sume,
                           const float* __restrict__ Wg, const float* __restrict__ bg,
                           const float* __restrict__ Wgn, const float* __restrict__ bgn,
                           const float* __restrict__ Wge, const float* __restrict__ bge,
                           const float* __restrict__ Wf, const float* __restrict__ bfv,
                           float* __restrict__ outg) {
    __shared__ float s_tmp[384];
    int r = blockIdx.x;
    int c = threadIdx.x;
    float a0 = 0.f, a1 = 0.f, a2 = 0.f;
    for (int k = 0; k < 128; k++) {
        a0 += glbs[r * 128 + k] * Wg[k * 128 + c];
        a1 += sumn[r * 128 + k] * Wgn[k * 128 + c];
        a2 += sume[r * 128 + k] * Wge[k * 128 + c];
    }
    s_tmp[c]       = lrelu(a0 + bg[c]);
    s_tmp[128 + c] = lrelu(a1 + bgn[c]);
    s_tmp[256 + c] = lrelu(a2 + bge[c]);
    __syncthreads();
    float a = 0.f;
    for (int k = 0; k < 384; k++) a += s_tmp[k] * Wf[k * 128 + c];
    outg[r * 128 + c] = lrelu(a + bfv[c]);
}

// ---------------- fused per-edge MLP over receiver-sorted edges ----------------
// block = 128 sorted edges, 512 threads = 8 waves (2M x 4N)
__launch_bounds__(512, 2)
__global__ void edge_mlp(const unsigned short* __restrict__ nodes_bf,
                         const float* __restrict__ edges,
                         const unsigned short* __restrict__ glbs_bf,
                         const int* __restrict__ senders, const int* __restrict__ receivers,
                         const int* __restrict__ sorted_eid,
                         const int* __restrict__ n_edge, int G,
                         const short* __restrict__ W0T, const short* __restrict__ W1T,
                         const float* __restrict__ b0c, const float* __restrict__ b1c,
                         float* __restrict__ out_nodes, float* __restrict__ out_edges) {
    __shared__ __align__(16) char sX[128 * 1024];
    __shared__ int s_eid[128], s_snd[128], s_recv[128], s_gid[128];

    const int tid  = threadIdx.x;
    const int lane = tid & 63;
    const int wid  = tid >> 6;
    const int wm   = wid >> 2;
    const int wn   = wid & 3;
    const int l15  = lane & 15;
    const int lk   = lane >> 4;
    const int base = blockIdx.x * 128;

    // cumulative edge counts (graph id by ORIGINAL edge index)
    int s_ = 0;
    int cu0 = 0x7fffffff, cu1 = 0x7fffffff, cu2 = 0x7fffffff, cu3 = 0x7fffffff;
    int cu4 = 0x7fffffff, cu5 = 0x7fffffff, cu6 = 0x7fffffff, cu7 = 0x7fffffff;
#define CUF(I, CU) if (I < G) { s_ += n_edge[I]; CU = s_; }
    CUF(0, cu0) CUF(1, cu1) CUF(2, cu2) CUF(3, cu3)
    CUF(4, cu4) CUF(5, cu5) CUF(6, cu6) CUF(7, cu7)
#undef CUF

    if (tid < 128) {
        int eid = sorted_eid[base + tid];
        s_eid[tid]  = eid;
        s_snd[tid]  = senders[eid];
        s_recv[tid] = receivers[eid];
        s_gid[tid]  = (eid >= cu0) + (eid >= cu1) + (eid >= cu2) + (eid >= cu3)
                    + (eid >= cu4) + (eid >= cu5) + (eid >= cu6) + (eid >= cu7);
    }
    __syncthreads();

    // ---- stage X into LDS (each wave stages one row per round) ----
#pragma unroll
    for (int r = 0; r < 16; ++r) {
        const int e   = r * 8 + wid;    // wave-uniform row
        const int eid = s_eid[e];
        const int snd = s_snd[e];
        const int rcv = s_recv[e];
        const int g   = s_gid[e];
        char* dst = sX + e * 1024;      // linear dst; HW adds lane*16
        if (lk == 2) {
            // edges are f32: load+convert+swizzled ds_write
            const float* fp = edges + (long)eid * 128 + l15 * 8;
            float4 v0 = *(const float4*)fp;
            float4 v1 = *(const float4*)(fp + 4);
            short8 a;
            a[0] = f2bf(v0.x); a[1] = f2bf(v0.y); a[2] = f2bf(v0.z); a[3] = f2bf(v0.w);
            a[4] = f2bf(v1.x); a[5] = f2bf(v1.y); a[6] = f2bf(v1.z); a[7] = f2bf(v1.w);
            *(short8*)(sX + e * 1024 + ((lane * 16) ^ ((e & 7) << 4))) = a;
        } else {
            // bf16 sources: glds, source pre-swizzled
            const int w = l15 ^ (e & 7);
            const unsigned short* bp = (lk == 0) ? nodes_bf + (long)snd * 128
                                     : (lk == 1) ? nodes_bf + (long)rcv * 128
                                                 : glbs_bf + (long)g * 128;
            __builtin_amdgcn_global_load_lds((g_u32*)(bp + w * 8), (l_u32*)dst, 16, 0, 0);
        }
    }
    __syncthreads();

    // ---- layer 1: X[128x512] @ W0c[512x512] ----
    f32x4 acc[4][8];
#pragma unroll
    for (int mt = 0; mt < 4; ++mt)
#pragma unroll
        for (int nt = 0; nt < 8; ++nt) acc[mt][nt] = (f32x4){0.f, 0.f, 0.f, 0.f};

#pragma unroll
    for (int t = 0; t < 16; ++t) {
        short8 bfr[8];
#pragma unroll
        for (int nt = 0; nt < 8; ++nt) {
            int n = wn * 128 + nt * 16 + l15;
            bfr[nt] = *(const short8*)(W0T + (long)n * 512 + t * 32 + lk * 8);
        }
#pragma unroll
        for (int mt = 0; mt < 4; ++mt) {
            int row = wm * 64 + mt * 16 + l15;
            short8 af = *(const short8*)(sX + row * 1024 + ((t * 64 + lk * 16) ^ ((row & 7) << 4)));
#pragma unroll
            for (int nt = 0; nt < 8; ++nt)
                acc[mt][nt] = __builtin_amdgcn_mfma_f32_16x16x32_bf16(af, bfr[nt], acc[mt][nt], 0, 0, 0);
        }
    }
    __syncthreads();

    // bias + leaky + bf16 -> LDS H (same geometry/swizzle as X)
#pragma unroll
    for (int nt = 0; nt < 8; ++nt) {
        int col = wn * 128 + nt * 16 + l15;
        float bias = b0c[col];
#pragma unroll
        for (int mt = 0; mt < 4; ++mt) {
#pragma unroll
            for (int q = 0; q < 4; ++q) {
                int row = wm * 64 + mt * 16 + lk * 4 + q;
                float v = lrelu(acc[mt][nt][q] + bias);
                *(short*)(sX + row * 1024 + ((col * 2) ^ ((row & 7) << 4))) = f2bf(v);
            }
        }
    }
    __syncthreads();

    // ---- layer 2 ----
    const int branch = wn >> 1;  // 0 = node-msg, 1 = edge-update
    const int halfn  = wn & 1;
    f32x4 acc2[4][4];
#pragma unroll
    for (int mt = 0; mt < 4; ++mt)
#pragma unroll
        for (int nt = 0; nt < 4; ++nt) acc2[mt][nt] = (f32x4){0.f, 0.f, 0.f, 0.f};

#pragma unroll
    for (int kt = 0; kt < 8; ++kt) {
        short8 bfr2[4];
#pragma unroll
        for (int nt = 0; nt < 4; ++nt) {
            int ncl = halfn * 64 + nt * 16 + l15;
            bfr2[nt] = *(const short8*)(W1T + (long)(branch * 128 + ncl) * 256 + kt * 32 + lk * 8);
        }
#pragma unroll
        for (int mt = 0; mt < 4; ++mt) {
            int row = wm * 64 + mt * 16 + l15;
            int kbyte = (branch * 256 + kt * 32 + lk * 8) * 2;
            short8 af = *(const short8*)(sX + row * 1024 + (kbyte ^ ((row & 7) << 4)));
#pragma unroll
            for (int nt = 0; nt < 4; ++nt)
                acc2[mt][nt] = __builtin_amdgcn_mfma_f32_16x16x32_bf16(af, bfr2[nt], acc2[mt][nt], 0, 0, 0);
        }
    }
    __syncthreads();  // H reads done; reuse sX[0..64KB) as f32 msg buffer

    // epilogue: msgs -> LDS (swizzled), edge-updates -> global
#pragma unroll
    for (int nt = 0; nt < 4; ++nt) {
        int ncl = halfn * 64 + nt * 16 + l15;
        float bias = b1c[branch * 128 + ncl];
#pragma unroll
        for (int mt = 0; mt < 4; ++mt) {
#pragma unroll
            for (int q = 0; q < 4; ++q) {
                int row = wm * 64 + mt * 16 + lk * 4 + q;
                float v = lrelu(acc2[mt][nt][q] + bias);
                if (branch == 0) {
                    // msg[row][ncl], 64B-block XOR swizzle on (row>>2)&3
                    *(float*)(sX + row * 512 + ((ncl * 4) ^ (((row >> 2) & 3) << 6))) = v;
                } else {
                    out_edges[(long)s_eid[row] * D_ + ncl] = v;
                }
            }
        }
    }
    __syncthreads();

    // segmented reduction over sorted receivers: one atomic per (segment x col)
    {
        int c  = tid & 127;
        int qr = tid >> 7;        // 0..3 -> rows [qr*32, qr*32+32)
        int r0 = qr * 32, r1 = r0 + 32;
        float acc_s = 0.f;
        int cur = s_recv[r0];
        for (int r = r0; r < r1; ++r) {
            int rc = s_recv[r];
            if (rc != cur) {
                atomicAdd(&out_nodes[(long)cur * D_ + c], acc_s);
                acc_s = 0.f; cur = rc;
            }
            acc_s += *(const float*)(sX + r * 512 + ((c * 4) ^ (((r >> 2) & 3) << 6)));
        }
        atomicAdd(&out_nodes[(long)cur * D_ + c], acc_s);
    }
}

extern "C" void kernel_launch(void* const* d_in, const int* in_sizes, int n_in,
                              void* d_out, int out_size, void* d_ws, size_t ws_size,
                              hipStream_t stream) {
    const float* nodes     = (const float*)d_in[0];
    const float* edges     = (const float*)d_in[1];
    const float* glbs      = (const float*)d_in[2];
    const int*   senders   = (const int*)d_in[3];
    const int*   receivers = (const int*)d_in[4];
    const int*   n_node    = (const int*)d_in[5];
    const int*   n_edge    = (const int*)d_in[6];
    const float* Wn0 = (const float*)d_in[7];
    const float* bn0 = (const float*)d_in[8];
    const float* Wn1 = (const float*)d_in[9];
    const float* bn1 = (const float*)d_in[10];
    const float* We0 = (const float*)d_in[11];
    const float* be0 = (const float*)d_in[12];
    const float* We1 = (const float*)d_in[13];
    const float* be1 = (const float*)d_in[14];
    const float* Wgn = (const float*)d_in[15];
    const float* bgn = (const float*)d_in[16];
    const float* Wge = (const float*)d_in[17];
    const float* bge = (const float*)d_in[18];
    const float* Wg  = (const float*)d_in[19];
    const float* bg  = (const float*)d_in[20];
    const float* Wf  = (const float*)d_in[21];
    const float* bfv = (const float*)d_in[22];

    const int N = in_sizes[0] / 128;
    const int E = in_sizes[1] / 128;
    const int G = in_sizes[2] / 128;

    char*  ws   = (char*)d_ws;
    short* W0T  = (short*)(ws);                      // 524288 B
    short* W1T  = (short*)(ws + 524288);             // 131072 B
    float* b0c  = (float*)(ws + 655360);             // 2048 B
    float* b1c  = (float*)(ws + 657408);             // 1024 B
    float* sumn = (float*)(ws + 658432);             // 4096 B
    float* sume = (float*)(ws + 662528);             // 4096 B
    unsigned short* glbs_bf  = (unsigned short*)(ws + 666624);   // 2048 B
    unsigned short* nodes_bf = (unsigned short*)(ws + 669696);   // N*256 B = 6.4 MB
    char*  ws2  = ws + 669696 + (size_t)N * 256;
    int* cnt        = (int*)(ws2);                   // N*4
    int* tmp_off    = (int*)(ws2 + (size_t)N * 4);   // N*4
    int* sorted_eid = (int*)(ws2 + (size_t)N * 8);   // E*4

    float* out_nodes = (float*)d_out;
    float* out_edges = out_nodes + (long)N * 128;
    float* out_glb   = out_edges + (long)E * 128;

    hipMemsetAsync(out_nodes, 0, (size_t)N * 128 * sizeof(float), stream);
    hipMemsetAsync(sumn, 0, 8192, stream);
    hipMemsetAsync(cnt, 0, (size_t)N * 4, stream);

    const long nq = (long)N * 32;
    const long prep_items = nq + 512 * 512 + 256 * 256 + 768 + 1024;
    prep<<<(int)((prep_items + 255) / 256), 256, 0, stream>>>(
        Wn0, We0, Wn1, We1, bn0, be0, bn1, be1, nodes, glbs, nq,
        W0T, W1T, b0c, b1c, nodes_bf, glbs_bf);

    hist_recv<<<(E + 255) / 256, 256, 0, stream>>>(receivers, E, cnt);
    scan_counts<<<1, 256, 0, stream>>>(cnt, N, tmp_off);
    place_edges<<<(E + 255) / 256, 256, 0, stream>>>(receivers, E, tmp_off, sorted_eid);

    edge_mlp<<<E / 128, 512, 0, stream>>>(nodes_bf, edges, glbs_bf, senders, receivers,
                                          sorted_eid, n_edge, G,
                                          W0T, W1T, b0c, b1c, out_nodes, out_edges);

    seg_sum<<<(N + 127) / 128, 256, 0, stream>>>(nodes, n_node, G, N, 128, sumn);
    seg_sum<<<(E + 255) / 256, 256, 0, stream>>>(edges, n_edge, G, E, 256, sume);

    global_mlp<<<G, 128, 0, stream>>>(glbs, sumn, sume, Wg, bg, Wgn, bgn, Wge, bge, Wf, bfv,
                                      out_glb);
}